// Round 16
// baseline (1669.919 us; speedup 1.0000x reference)
//
#include <hip/hip_runtime.h>

#define NB 32
#define TT 512
#define SS 5
#define CC 512
#define UU 256
#define NEGV -1e30f
#define LCH 8                  // timesteps per chunk
#define NCH (TT / LCH)         // 64 chunks
#define PKW 12                 // packed row width: e0..e3, b0..b4, pad x3
#define PKL 13                 // LDS row width (odd -> conflict-free stride)
#define PRODB (NB * TT * SS / 8)   // 10240 producer blocks (8 rows each)
#define PER_N (PRODB / NB)         // 320 producer blocks per batch item
#define SCANB (2 * NB)             // 64 scan blocks: one per (n, sem)

// ---------------------------------------------------------------------------
// Semiring helpers.
// ---------------------------------------------------------------------------
__device__ __forceinline__ float lse_corr(float x, float y) {
    return __logf(1.0f + __expf(-fabsf(x - y)));
}
template <bool MAXSEM>
__device__ __forceinline__ float combf(float x, float y) {
    return MAXSEM ? fmaxf(x, y) : fmaxf(x, y) + lse_corr(x, y);
}
template <bool MAXSEM>
__device__ __forceinline__ float fold5(float t0, float t1, float t2,
                                       float t3, float t4) {
    float c01 = combf<MAXSEM>(t0, t1);
    float c23 = combf<MAXSEM>(t2, t3);
    return combf<MAXSEM>(combf<MAXSEM>(c01, c23), t4);
}

// ---------------------------------------------------------------------------
// Scan body (r15 math, verbatim): chunk chains + pairwise composition tree.
// ---------------------------------------------------------------------------
template <bool MAXSEM>
__device__ __forceinline__ void chain_and_tree(
    const float* __restrict__ pk2,
    float* __restrict__ matA, float* __restrict__ matB,
    float* __restrict__ partials, int sid, int tid)
{
    // ---- chunk chain: threads 0..319 = (c = tid&63, j = tid>>6) ----
    if (tid < 320) {
        const int j = tid >> 6;           // basis column, wave-uniform
        const int c = tid & 63;           // chunk

        float v0 = (j == 0) ? 0.0f : NEGV;
        float v1 = (j == 1) ? 0.0f : NEGV;
        float v2 = (j == 2) ? 0.0f : NEGV;
        float v3 = (j == 3) ? 0.0f : NEGV;
        float v4 = (j == 4) ? 0.0f : NEGV;

#pragma unroll
        for (int i = 0; i < LCH; ++i) {
            const float* row = pk2 + (i * 64 + c) * PKL;
            float e0 = row[0], e1 = row[1], e2 = row[2], e3 = row[3];

            v1 = combf<MAXSEM>(v1, v0 + e0);
            v2 = combf<MAXSEM>(v2, v1 + e1);
            v3 = combf<MAXSEM>(v3, v2 + e2);
            v4 = combf<MAXSEM>(v4, v3 + e3);

            if (c * LCH + i < TT - 1) {          // per-lane predicated
                float b0 = row[4], b1 = row[5], b2 = row[6];
                float b3 = row[7], b4 = row[8];
                bool sh = row[9] != 0.0f;        // delta in {0,1}
                float n0 = sh ? v1 + b1 : v0 + b0;
                float n1 = sh ? v2 + b2 : v1 + b1;
                float n2 = sh ? v3 + b3 : v2 + b2;
                float n3 = sh ? v4 + b4 : v3 + b3;
                float n4 = sh ? NEGV    : v4 + b4;
                v0 = n0; v1 = n1; v2 = n2; v3 = n3; v4 = n4;
            }
        }
        float* outp = matA + c * 25 + j * 5;     // col-major m[j*5+s]
        outp[0] = v0; outp[1] = v1; outp[2] = v2; outp[3] = v3; outp[4] = v4;
    }
    __syncthreads();

    // ---- pairwise composition tree: 64 -> 1 ----
    float* src = matA;
    float* dst = matB;
    int m = NCH;
    while (m > 1) {
        int pairs = m >> 1;
        for (int item = tid; item < pairs * 25; item += 512) {
            int p = item / 25, e = item - p * 25;
            int j = e / 5, s = e - j * 5;
            const float* A = src + (2 * p) * 25;       // earlier chunk
            const float* B = src + (2 * p + 1) * 25;   // later chunk
            float t0 = B[s]      + A[j * 5 + 0];
            float t1 = B[5 + s]  + A[j * 5 + 1];
            float t2 = B[10 + s] + A[j * 5 + 2];
            float t3 = B[15 + s] + A[j * 5 + 3];
            float t4 = B[20 + s] + A[j * 5 + 4];
            dst[item] = fold5<MAXSEM>(t0, t1, t2, t3, t4);
        }
        __syncthreads();
        float* tmp = src; src = dst; dst = tmp;
        m = pairs;
    }
    // v_init = e0 -> answer = -M_tot[4][0] = -src[4]
    if (tid == 0) partials[sid] = -src[4];
}

// ---------------------------------------------------------------------------
// Fused kernel: 10240 producer blocks (row LSE) + 64 scan blocks that
// overlap A's tail. Per-n release counters; tail-placed spinners (s_sleep)
// can never starve producers -> deadlock-free.
// ---------------------------------------------------------------------------
__global__ __launch_bounds__(512) void fused_kernel(
    const float* __restrict__ logits,   // [N][T][S][C]
    const int*   __restrict__ ranges,   // [N][T][S]
    const int*   __restrict__ y,        // [N][U]
    float*       __restrict__ packed,   // [N][T][PKW]
    float*       __restrict__ partials, // [SCANB]
    int*         __restrict__ ncnt,     // [NB] per-n producer counters
    int*         __restrict__ cnt2,     // [1]  scan completion counter
    float*       __restrict__ out)      // [2]
{
    __shared__ float pk2[LCH * 64 * PKL];        // 26.6 KB
    __shared__ float matA[NCH * 25];             // 6.4 KB
    __shared__ float matB[(NCH / 2) * 25];       // 3.2 KB
    __shared__ int   amLast;

    const int tid = threadIdx.x;
    const int bid = blockIdx.x;

    if (bid < PRODB) {
        // ================= producer: 8 rows of logits =================
        const int lane = tid & 63;
        const int row  = bid * 8 + (tid >> 6);   // 0..81919, same n per block
        const float* rowp = logits + (size_t)row * CC;

        float4 a = *(const float4*)(rowp + lane * 4);
        float4 b = *(const float4*)(rowp + 256 + lane * 4);

        float s = __expf(a.x) + __expf(a.y) + __expf(a.z) + __expf(a.w)
                + __expf(b.x) + __expf(b.y) + __expf(b.z) + __expf(b.w);
#pragma unroll
        for (int off = 32; off; off >>= 1)
            s += __shfl_xor(s, off);

        const int   rg    = ranges[row];
        const int   n     = row / (TT * SS);
        const int   sy    = y[n * UU + rg];
        const float emraw = rowp[sy];
        const float blraw = rowp[0];
        const float lse   = __logf(s);

        if (lane == 0) {
            int loc  = row - n * (TT * SS);
            int t    = loc / SS;
            int sidx = loc - t * SS;
            float* dst = packed + ((size_t)n * TT + t) * PKW;
            if (sidx < 4) dst[sidx] = emraw - lse;
            dst[4 + sidx] = blraw - lse;
        }

        // completion: one release-add per block on this n's counter
        __syncthreads();
        __threadfence();
        if (tid == 0)
            __hip_atomic_fetch_add(&ncnt[bid / PER_N], 1, __ATOMIC_RELEASE,
                                   __HIP_MEMORY_SCOPE_AGENT);
        return;
    }

    // ================= scan block: one (n, sem) =================
    const int sid = bid - PRODB;                 // 0..63
    const int n   = sid & 31;
    const int sem = sid >> 5;                    // 0 = lse, 1 = max

    if (tid == 0) {
        while (__hip_atomic_load(&ncnt[n], __ATOMIC_ACQUIRE,
                                 __HIP_MEMORY_SCOPE_AGENT) < PER_N)
            __builtin_amdgcn_s_sleep(2);
    }
    __syncthreads();                             // all threads ordered after acquire

    // ---- stage: conflict-free LDS scatter (r15 layout) ----
    {
        const float* gsrc = packed + (size_t)n * TT * PKW;
        for (int idx = tid; idx < TT * PKW; idx += 512) {
            int t = idx / PKW, k = idx - t * PKW;
            if (k < 9) {
                int c = t >> 3, i = t & 7;
                pk2[(i * 64 + c) * PKL + k] = gsrc[idx];
            }
        }
        for (int t = tid; t < TT; t += 512) {
            int c = t >> 3, i = t & 7;
            float sh = 0.0f;
            if (t < TT - 1)
                sh = (ranges[(n * TT + t) * SS] !=
                      ranges[(n * TT + t + 1) * SS]) ? 1.0f : 0.0f;
            pk2[(i * 64 + c) * PKL + 9] = sh;
        }
    }
    __syncthreads();

    if (sem == 0) chain_and_tree<false>(pk2, matA, matB, partials, sid, tid);
    else          chain_and_tree<true >(pk2, matA, matB, partials, sid, tid);

    // ---- completion: last finishing scan block sums partials -> out ----
    __syncthreads();
    __threadfence();
    if (tid == 0) {
        int old = __hip_atomic_fetch_add(cnt2, 1, __ATOMIC_ACQ_REL,
                                         __HIP_MEMORY_SCOPE_AGENT);
        amLast = (old == SCANB - 1);
    }
    __syncthreads();
    if (!amLast) return;
    __threadfence();                             // reader-side acquire

    if (tid < 64) {
        float v = partials[tid];                 // lanes 0-31: lse, 32-63: max
#pragma unroll
        for (int off = 16; off; off >>= 1)
            v += __shfl_xor(v, off);
        if ((tid & 31) == 0)
            out[tid >> 5] = v;                   // out[0]=pruned, out[1]=one_best
    }
}

extern "C" void kernel_launch(void* const* d_in, const int* in_sizes, int n_in,
                              void* d_out, int out_size, void* d_ws, size_t ws_size,
                              hipStream_t stream) {
    const float* logits = (const float*)d_in[0];
    const int*   ranges = (const int*)d_in[1];
    const int*   y      = (const int*)d_in[2];
    // d_in[3] = x_lens, unused (reference ignores it; all == T)

    float* packed   = (float*)d_ws;                       // NB*TT*PKW floats
    float* partials = packed + (size_t)NB * TT * PKW;     // SCANB floats
    int*   ncnt     = (int*)(partials + SCANB);           // NB ints
    int*   cnt2     = ncnt + NB;                          // 1 int
    float* out      = (float*)d_out;

    // zero the ordering counters (in-graph, deterministic)
    hipMemsetAsync(ncnt, 0, (NB + 1) * sizeof(int), stream);

    hipLaunchKernelGGL(fused_kernel, dim3(PRODB + SCANB), dim3(512), 0, stream,
                       logits, ranges, y, packed, partials, ncnt, cnt2, out);
}

// Round 17
// 96.599 us; speedup vs baseline: 17.2871x; 17.2871x over previous
//
#include <hip/hip_runtime.h>

#define NB 32
#define TT 512
#define SS 5
#define CC 512
#define UU 256
#define NEGV -1e30f
#define LCH 8                  // timesteps per chunk
#define NCH (TT / LCH)         // 64 chunks
#define PKW 12                 // packed row width: e0..e3, b0..b4, pad x3
#define PKL 13                 // LDS row width (odd -> conflict-free stride)
#define TREEB (2 * NB)         // 64 scan blocks: one per (n, sem)
#define NREP 4                 // scan replicas (attribution probe)

// ---------------------------------------------------------------------------
// Kernel A: per-row sum-exp over C=512 (no-max LSE). At HBM roofline
// (27.6 us, round-10 marginal probe; 6.08 TB/s). Zeroes NREP counters.
// ---------------------------------------------------------------------------
__global__ __launch_bounds__(512) void row_lse_kernel(
    const float* __restrict__ logits,   // [N][T][S][C]
    const int*   __restrict__ ranges,   // [N][T][S]
    const int*   __restrict__ y,        // [N][U]
    float*       __restrict__ packed,   // [N][T][PKW]
    int*         __restrict__ cnt)      // NREP completion counters
{
    if (blockIdx.x == 0 && threadIdx.x < NREP) cnt[threadIdx.x] = 0;

    const int lane = threadIdx.x & 63;
    const int row  = blockIdx.x * 8 + (threadIdx.x >> 6);  // 0..81919
    const float* rowp = logits + (size_t)row * CC;

    float4 a = *(const float4*)(rowp + lane * 4);          // floats [0,256)
    float4 b = *(const float4*)(rowp + 256 + lane * 4);    // floats [256,512)

    float s = __expf(a.x) + __expf(a.y) + __expf(a.z) + __expf(a.w)
            + __expf(b.x) + __expf(b.y) + __expf(b.z) + __expf(b.w);
#pragma unroll
    for (int off = 32; off; off >>= 1)
        s += __shfl_xor(s, off);

    const int   rg    = ranges[row];
    const int   n     = row / (TT * SS);
    const int   sy    = y[n * UU + rg];
    const float emraw = rowp[sy];
    const float blraw = rowp[0];
    const float lse   = __logf(s);

    if (lane == 0) {
        int loc  = row - n * (TT * SS);
        int t    = loc / SS;
        int sidx = loc - t * SS;
        float* dst = packed + ((size_t)n * TT + t) * PKW;
        if (sidx < 4) dst[sidx] = emraw - lse;   // em used only for s=0..3
        dst[4 + sidx] = blraw - lse;             // bl for s=0..4
    }
}

// ---------------------------------------------------------------------------
// Semiring helpers.
// ---------------------------------------------------------------------------
__device__ __forceinline__ float lse_corr(float x, float y) {
    return __logf(1.0f + __expf(-fabsf(x - y)));
}
template <bool MAXSEM>
__device__ __forceinline__ float combf(float x, float y) {
    return MAXSEM ? fmaxf(x, y) : fmaxf(x, y) + lse_corr(x, y);
}
template <bool MAXSEM>
__device__ __forceinline__ float fold5(float t0, float t1, float t2,
                                       float t3, float t4) {
    float c01 = combf<MAXSEM>(t0, t1);
    float c23 = combf<MAXSEM>(t2, t3);
    return combf<MAXSEM>(combf<MAXSEM>(c01, c23), t4);
}

// ---------------------------------------------------------------------------
// Kernel B (r15 verbatim): whole scan, one block per (n, sem).
// Launched NREP x this round with distinct counters (marginal-cost probe).
// ---------------------------------------------------------------------------
template <bool MAXSEM>
__device__ __forceinline__ void chain_and_tree(
    const float* __restrict__ pk2,
    float* __restrict__ matA, float* __restrict__ matB,
    float* __restrict__ partials, int bid, int tid)
{
    // ---- chunk chain: thread (c = tid&63, j = tid>>6) ----
    {
        const int j = tid >> 6;           // basis column, wave-uniform
        const int c = tid & 63;           // chunk

        float v0 = (j == 0) ? 0.0f : NEGV;
        float v1 = (j == 1) ? 0.0f : NEGV;
        float v2 = (j == 2) ? 0.0f : NEGV;
        float v3 = (j == 3) ? 0.0f : NEGV;
        float v4 = (j == 4) ? 0.0f : NEGV;

#pragma unroll
        for (int i = 0; i < LCH; ++i) {
            const float* row = pk2 + (i * 64 + c) * PKL;
            float e0 = row[0], e1 = row[1], e2 = row[2], e3 = row[3];

            v1 = combf<MAXSEM>(v1, v0 + e0);
            v2 = combf<MAXSEM>(v2, v1 + e1);
            v3 = combf<MAXSEM>(v3, v2 + e2);
            v4 = combf<MAXSEM>(v4, v3 + e3);

            if (c * LCH + i < TT - 1) {          // per-lane predicated
                float b0 = row[4], b1 = row[5], b2 = row[6];
                float b3 = row[7], b4 = row[8];
                bool sh = row[9] != 0.0f;        // delta in {0,1}
                float n0 = sh ? v1 + b1 : v0 + b0;
                float n1 = sh ? v2 + b2 : v1 + b1;
                float n2 = sh ? v3 + b3 : v2 + b2;
                float n3 = sh ? v4 + b4 : v3 + b3;
                float n4 = sh ? NEGV    : v4 + b4;
                v0 = n0; v1 = n1; v2 = n2; v3 = n3; v4 = n4;
            }
        }
        float* outp = matA + c * 25 + j * 5;     // col-major m[j*5+s]
        outp[0] = v0; outp[1] = v1; outp[2] = v2; outp[3] = v3; outp[4] = v4;
    }
    __syncthreads();

    // ---- pairwise composition tree: 64 -> 1 ----
    float* src = matA;
    float* dst = matB;
    int m = NCH;
    while (m > 1) {
        int pairs = m >> 1;
        for (int item = tid; item < pairs * 25; item += 320) {
            int p = item / 25, e = item - p * 25;
            int j = e / 5, s = e - j * 5;
            const float* A = src + (2 * p) * 25;       // earlier chunk
            const float* B = src + (2 * p + 1) * 25;   // later chunk
            float t0 = B[s]      + A[j * 5 + 0];
            float t1 = B[5 + s]  + A[j * 5 + 1];
            float t2 = B[10 + s] + A[j * 5 + 2];
            float t3 = B[15 + s] + A[j * 5 + 3];
            float t4 = B[20 + s] + A[j * 5 + 4];
            dst[item] = fold5<MAXSEM>(t0, t1, t2, t3, t4);
        }
        __syncthreads();
        float* tmp = src; src = dst; dst = tmp;
        m = pairs;
    }
    // v_init = e0 -> answer = -M_tot[4][0] = -src[4]
    if (tid == 0) partials[bid] = -src[4];
}

__global__ __launch_bounds__(320) void scan_all(
    const float* __restrict__ packed,   // [N][T][PKW]
    const int*   __restrict__ ranges,   // [N][T][S]
    float*       __restrict__ partials, // [TREEB]
    int*         __restrict__ cnt,      // this replica's counter
    float*       __restrict__ out)      // [2]
{
    __shared__ float pk2[LCH * 64 * PKL];        // 26.6 KB
    __shared__ float matA[NCH * 25];             // 6.4 KB
    __shared__ float matB[(NCH / 2) * 25];       // 3.2 KB
    __shared__ int   amLast;

    const int tid = threadIdx.x;                 // 0..319
    const int bid = blockIdx.x;                  // 0..63
    const int n   = bid & 31;
    const int sem = bid >> 5;                    // 0 = lse, 1 = max

    // ---- stage: coalesced global read, conflict-free LDS scatter ----
    {
        const float* gsrc = packed + (size_t)n * TT * PKW;
        for (int idx = tid; idx < TT * PKW; idx += 320) {
            int t = idx / PKW, k = idx - t * PKW;
            if (k < 9) {
                int c = t >> 3, i = t & 7;
                pk2[(i * 64 + c) * PKL + k] = gsrc[idx];
            }
        }
        for (int t = tid; t < TT; t += 320) {
            int c = t >> 3, i = t & 7;
            float sh = 0.0f;
            if (t < TT - 1)
                sh = (ranges[(n * TT + t) * SS] !=
                      ranges[(n * TT + t + 1) * SS]) ? 1.0f : 0.0f;
            pk2[(i * 64 + c) * PKL + 9] = sh;
        }
    }
    __syncthreads();

    if (sem == 0) chain_and_tree<false>(pk2, matA, matB, partials, bid, tid);
    else          chain_and_tree<true >(pk2, matA, matB, partials, bid, tid);

    // ---- completion: last finishing block sums partials -> out ----
    __syncthreads();
    __threadfence();
    if (tid == 0) {
        int old = __hip_atomic_fetch_add(cnt, 1, __ATOMIC_ACQ_REL,
                                         __HIP_MEMORY_SCOPE_AGENT);
        amLast = (old == TREEB - 1);
    }
    __syncthreads();
    if (!amLast) return;
    __threadfence();                             // reader-side acquire

    if (tid < 64) {
        float v = partials[tid];                 // lanes 0-31: lse, 32-63: max
#pragma unroll
        for (int off = 16; off; off >>= 1)
            v += __shfl_xor(v, off);
        if ((tid & 31) == 0)
            out[tid >> 5] = v;                   // out[0]=pruned, out[1]=one_best
    }
}

extern "C" void kernel_launch(void* const* d_in, const int* in_sizes, int n_in,
                              void* d_out, int out_size, void* d_ws, size_t ws_size,
                              hipStream_t stream) {
    const float* logits = (const float*)d_in[0];
    const int*   ranges = (const int*)d_in[1];
    const int*   y      = (const int*)d_in[2];
    // d_in[3] = x_lens, unused (reference ignores it; all == T)

    float* packed   = (float*)d_ws;                       // NB*TT*PKW floats
    float* partials = packed + (size_t)NB * TT * PKW;     // TREEB floats
    int*   cnt      = (int*)(partials + TREEB);           // NREP ints
    float* out      = (float*)d_out;

    int rows = NB * TT * SS;                              // 81920
    hipLaunchKernelGGL(row_lse_kernel, dim3(rows / 8), dim3(512), 0, stream,
                       logits, ranges, y, packed, cnt);
    // ATTRIBUTION PROBE: NREP idempotent scan launches, distinct counters.
    // dur_us = 50.2 + (NREP-1) * t_scan  ->  timed-path cost of scan_all.
    for (int rep = 0; rep < NREP; ++rep) {
        hipLaunchKernelGGL(scan_all, dim3(TREEB), dim3(320), 0, stream,
                           packed, ranges, partials, cnt + rep, out);
    }
}

// Round 19
// 40.093 us; speedup vs baseline: 41.6507x; 2.4093x over previous
//
#include <hip/hip_runtime.h>

#define NB 32
#define TT 512
#define SS 5
#define CC 512
#define UU 256
#define NEGV -1e30f
#define LCH 4                  // timesteps per chunk
#define NCH (TT / LCH)         // 128 chunks
#define PKW 12                 // packed row width: e0..e3, b0..b4, dsh, pad
#define SCANB (2 * NB)         // 64 scan blocks: one per (n, sem)
#define LOG2E 1.4426950408889634f
#define LN2   0.6931471805599453f

// ---------------------------------------------------------------------------
// Kernel A: per-row sum-exp over C=512 (no-max LSE). At HBM roofline.
// Writes packed[n][t] = {em*log2e (s=0..3), bl*log2e (s=0..4), dsh} (base-2
// log domain). Shift flag dsh computed here (slot 9) so the scan kernel
// reads pure float4s.
// ---------------------------------------------------------------------------
__global__ __launch_bounds__(512) void row_lse_kernel(
    const float* __restrict__ logits,   // [N][T][S][C]
    const int*   __restrict__ ranges,   // [N][T][S]
    const int*   __restrict__ y,        // [N][U]
    float*       __restrict__ packed)   // [N][T][PKW]
{
    const int lane = threadIdx.x & 63;
    const int row  = blockIdx.x * 8 + (threadIdx.x >> 6);  // 0..81919
    const float* rowp = logits + (size_t)row * CC;

    float4 a = *(const float4*)(rowp + lane * 4);          // floats [0,256)
    float4 b = *(const float4*)(rowp + 256 + lane * 4);    // floats [256,512)

    float s = __expf(a.x) + __expf(a.y) + __expf(a.z) + __expf(a.w)
            + __expf(b.x) + __expf(b.y) + __expf(b.z) + __expf(b.w);
#pragma unroll
    for (int off = 32; off; off >>= 1)
        s += __shfl_xor(s, off);

    const int   rg    = ranges[row];
    const int   n     = row / (TT * SS);
    const int   sy    = y[n * UU + rg];
    const float emraw = rowp[sy];
    const float blraw = rowp[0];
    const float lse   = __logf(s);

    if (lane == 0) {
        int loc  = row - n * (TT * SS);
        int t    = loc / SS;
        int sidx = loc - t * SS;
        float* dst = packed + ((size_t)n * TT + t) * PKW;
        if (sidx < 4) dst[sidx] = (emraw - lse) * LOG2E;
        dst[4 + sidx] = (blraw - lse) * LOG2E;
        if (sidx == 0) {                       // rg == lb(t) for this row
            float sh = 0.0f;
            if (t < TT - 1)
                sh = (ranges[(n * TT + t + 1) * SS] != rg) ? 1.0f : 0.0f;
            dst[9] = sh;
        }
    }
}

// ---------------------------------------------------------------------------
// Semiring helpers — base-2 log domain (v_exp/v_log ARE base-2: no muls).
// ---------------------------------------------------------------------------
template <bool MAXSEM>
__device__ __forceinline__ float combf(float x, float y) {
    float m = fmaxf(x, y);
    if (MAXSEM) return m;
    return m + __log2f(1.0f + exp2f(-fabsf(x - y)));
}
template <bool MAXSEM>
__device__ __forceinline__ float fold5(float t0, float t1, float t2,
                                       float t3, float t4) {
    float c01 = combf<MAXSEM>(t0, t1);
    float c23 = combf<MAXSEM>(t2, t3);
    return combf<MAXSEM>(combf<MAXSEM>(c01, c23), t4);
}

// ---------------------------------------------------------------------------
// Kernel B: scan. 64 blocks x 640 threads; thread = (c = tid&127, j = tid>>7).
// Chain (depth 16) entirely from registers; 7-level tree in LDS; partials out
// via plain stores (no fences/atomics — kernel boundary orders visibility).
// ---------------------------------------------------------------------------
template <bool MAXSEM>
__device__ __forceinline__ void scan_body(
    const float* __restrict__ packed, float* __restrict__ matA,
    float* __restrict__ matB, float* __restrict__ partials,
    int n, int bid, int tid)
{
    const int c = tid & 127;            // chunk 0..127
    const int j = tid >> 7;             // basis column 0..4

    // ---- register prefetch: 4 timesteps x 3 float4 ----
    const float4* gb = (const float4*)(packed + ((size_t)n * TT + c * LCH) * PKW);
    float4 q0 = gb[0],  q1 = gb[1],  q2 = gb[2];
    float4 q3 = gb[3],  q4 = gb[4],  q5 = gb[5];
    float4 q6 = gb[6],  q7 = gb[7],  q8 = gb[8];
    float4 q9 = gb[9],  q10 = gb[10], q11 = gb[11];

    float v0 = (j == 0) ? 0.0f : NEGV;
    float v1 = (j == 1) ? 0.0f : NEGV;
    float v2 = (j == 2) ? 0.0f : NEGV;
    float v3 = (j == 3) ? 0.0f : NEGV;
    float v4 = (j == 4) ? 0.0f : NEGV;

#define STEP(eA, bA, cA, ti)                                            \
    {                                                                   \
        v1 = combf<MAXSEM>(v1, v0 + eA.x);                              \
        v2 = combf<MAXSEM>(v2, v1 + eA.y);                              \
        v3 = combf<MAXSEM>(v3, v2 + eA.z);                              \
        v4 = combf<MAXSEM>(v4, v3 + eA.w);                              \
        if (c * LCH + ti < TT - 1) {                                    \
            bool sh = cA.y != 0.0f;        /* slot 9 = dsh */           \
            float n0 = sh ? v1 + bA.y : v0 + bA.x;                      \
            float n1 = sh ? v2 + bA.z : v1 + bA.y;                      \
            float n2 = sh ? v3 + bA.w : v2 + bA.z;                      \
            float n3 = sh ? v4 + cA.x : v3 + bA.w;                      \
            float n4 = sh ? NEGV      : v4 + cA.x;                      \
            v0 = n0; v1 = n1; v2 = n2; v3 = n3; v4 = n4;                \
        }                                                               \
    }
    STEP(q0, q1, q2, 0)
    STEP(q3, q4, q5, 1)
    STEP(q6, q7, q8, 2)
    STEP(q9, q10, q11, 3)
#undef STEP

    {
        float* outp = matA + c * 25 + j * 5;     // col-major m[j*5+s]
        outp[0] = v0; outp[1] = v1; outp[2] = v2; outp[3] = v3; outp[4] = v4;
    }
    __syncthreads();

    // ---- pairwise composition tree: 128 -> 1 (7 levels) ----
    float* src = matA;
    float* dst = matB;
    int m = NCH;
    while (m > 1) {
        int pairs = m >> 1;
        for (int item = tid; item < pairs * 25; item += 640) {
            int p = item / 25, e = item - p * 25;
            int jj = e / 5, s = e - jj * 5;
            const float* A = src + (2 * p) * 25;       // earlier chunk
            const float* B = src + (2 * p + 1) * 25;   // later chunk
            float t0 = B[s]      + A[jj * 5 + 0];
            float t1 = B[5 + s]  + A[jj * 5 + 1];
            float t2 = B[10 + s] + A[jj * 5 + 2];
            float t3 = B[15 + s] + A[jj * 5 + 3];
            float t4 = B[20 + s] + A[jj * 5 + 4];
            dst[item] = fold5<MAXSEM>(t0, t1, t2, t3, t4);
        }
        __syncthreads();
        float* tmp = src; src = dst; dst = tmp;
        m = pairs;
    }
    // v_init = e0 -> answer = -M_tot[4][0] = -src[4]  (base-2 domain)
    if (tid == 0) partials[bid] = -src[4];
}

__global__ __launch_bounds__(640) void scan_all(
    const float* __restrict__ packed,   // [N][T][PKW]
    float*       __restrict__ partials) // [SCANB]
{
    __shared__ float matA[NCH * 25];            // 12.8 KB
    __shared__ float matB[(NCH / 2) * 25];      // 6.4 KB

    const int bid = blockIdx.x;                 // 0..63
    const int n   = bid & 31;
    const int sem = bid >> 5;                   // 0 = lse, 1 = max

    if (sem == 0) scan_body<false>(packed, matA, matB, partials, n, bid, threadIdx.x);
    else          scan_body<true >(packed, matA, matB, partials, n, bid, threadIdx.x);
}

// ---------------------------------------------------------------------------
// Kernel C: final reduce (64 partials -> 2 outputs, rescale base-2 -> e).
// ---------------------------------------------------------------------------
__global__ __launch_bounds__(64) void reduce_kernel(
    const float* __restrict__ partials, float* __restrict__ out)
{
    int tid = threadIdx.x;
    float v = partials[tid];             // lanes 0-31: lse, 32-63: max
#pragma unroll
    for (int off = 16; off; off >>= 1)
        v += __shfl_xor(v, off);
    if ((tid & 31) == 0)
        out[tid >> 5] = v * LN2;         // out[0]=pruned, out[1]=one_best
}

extern "C" void kernel_launch(void* const* d_in, const int* in_sizes, int n_in,
                              void* d_out, int out_size, void* d_ws, size_t ws_size,
                              hipStream_t stream) {
    const float* logits = (const float*)d_in[0];
    const int*   ranges = (const int*)d_in[1];
    const int*   y      = (const int*)d_in[2];
    // d_in[3] = x_lens, unused (reference ignores it; all == T)

    float* packed   = (float*)d_ws;                       // NB*TT*PKW floats
    float* partials = packed + (size_t)NB * TT * PKW;     // SCANB floats
    float* out      = (float*)d_out;

    int rows = NB * TT * SS;                              // 81920
    hipLaunchKernelGGL(row_lse_kernel, dim3(rows / 8), dim3(512), 0, stream,
                       logits, ranges, y, packed);
    hipLaunchKernelGGL(scan_all, dim3(SCANB), dim3(640), 0, stream,
                       packed, partials);
    hipLaunchKernelGGL(reduce_kernel, dim3(1), dim3(64), 0, stream,
                       partials, out);
}